// Round 1
// baseline (1769.510 us; speedup 1.0000x reference)
//
#include <hip/hip_runtime.h>
#include <math.h>

#define T_LEN   16384
#define NB      2
#define RCH     64
#define GCH     128
#define SCH     64
#define FCH     80
#define OUTC    256
#define NLAYERS 24
#define TFRAMES 68
#define TILE_T  64

// ---------------------------------------------------------------------------
// Embedding (one-hot @ first_W == gather) + zero-init skip accumulator
// ---------------------------------------------------------------------------
__global__ void k_embed(const int* __restrict__ x, const float* __restrict__ firstW,
                        const float* __restrict__ firstb,
                        float* __restrict__ out, float* __restrict__ skip) {
    int idx = blockIdx.x * 256 + threadIdx.x;
    if (idx >= NB * RCH * T_LEN) return;
    int t = idx & (T_LEN - 1);
    int c = (idx >> 14) & (RCH - 1);
    int b = idx >> 20;
    int xs = (t == 0) ? 0 : x[b * T_LEN + t - 1];   // shift-right, pad value 0 -> class 0
    out[idx] = firstW[c * OUTC + xs] + firstb[c];
    skip[idx] = 0.0f;
}

// ---------------------------------------------------------------------------
// ConvIn: valid conv, kernel 5, (B,80,68) -> (B,80,64)
// ---------------------------------------------------------------------------
__global__ void k_convin(const float* __restrict__ feat, const float* __restrict__ W,
                         float* __restrict__ f0) {
    int idx = blockIdx.x * 256 + threadIdx.x;
    if (idx >= NB * FCH * 64) return;
    int t = idx & 63;
    int o = (idx >> 6) % FCH;
    int b = idx / (64 * FCH);
    const float* fb = feat + b * FCH * TFRAMES;
    const float* wo = W + o * FCH * 5;
    float acc = 0.f;
    for (int i = 0; i < FCH; ++i) {
        const float* fi = fb + i * TFRAMES + t;
        const float* wi = wo + i * 5;
#pragma unroll
        for (int k = 0; k < 5; ++k) acc += fi[k] * wi[k];
    }
    f0[idx] = acc;
}

// ---------------------------------------------------------------------------
// One upsample stage: repeat x4 then smooth with kernel 9, zero-padded
// ---------------------------------------------------------------------------
__global__ void k_up(const float* __restrict__ in, float* __restrict__ out,
                     const float* __restrict__ kern, int Tin) {
    int Tout = Tin * 4;
    int idx = blockIdx.x * 256 + threadIdx.x;
    if (idx >= NB * FCH * Tout) return;
    int t = idx % Tout;
    int bc = idx / Tout;
    const float* ib = in + bc * Tin;
    float acc = 0.f;
#pragma unroll
    for (int k = 0; k < 9; ++k) {
        int u = t + k - 4;
        if (u >= 0 && u < Tout) acc += kern[k] * ib[u >> 2];
    }
    out[idx] = acc;
}

// ---------------------------------------------------------------------------
// Pack weights into GEMM-friendly transposed layouts.
// AT[l][k][o]: k in [0,192): k = tap*64 + c -> conv_W[l][o][c][tap]
//             k in [192,272): cond_W[l][o][k-192]
// SRT[l][c][o2]: o2<64 -> skip_W[l][o2][c]; o2>=64 -> res_W[l][o2-64][c]
// ---------------------------------------------------------------------------
__global__ void k_pack(const float* __restrict__ convW, const float* __restrict__ condW,
                       const float* __restrict__ skipW, const float* __restrict__ resW,
                       float* __restrict__ AT, float* __restrict__ SRT) {
    int idx = blockIdx.x * 256 + threadIdx.x;
    const int nAT = NLAYERS * 272 * 128;
    const int nSR = NLAYERS * 64 * 128;
    if (idx < nAT) {
        int o = idx & 127;
        int k = (idx >> 7) % 272;
        int l = idx / (272 * 128);
        float v;
        if (k < 192) {
            int tap = k >> 6, c = k & 63;
            v = convW[((l * GCH + o) * RCH + c) * 3 + tap];
        } else {
            v = condW[(l * GCH + o) * FCH + (k - 192)];
        }
        AT[idx] = v;
    } else if (idx < nAT + nSR) {
        int j = idx - nAT;
        int o = j & 127;
        int c = (j >> 7) & 63;
        int l = j / (64 * 128);
        SRT[j] = (o < 64) ? skipW[(l * SCH + o) * 64 + c]
                          : resW[(l * RCH + (o - 64)) * 64 + c];
    }
}

// ---------------------------------------------------------------------------
// One WaveNet layer, fully fused:
//   h = dilated_causal_conv(out) + cond_W@f + conv_b
//   z = tanh(h[:64]) * sigmoid(h[64:])
//   skip += skip_W@z + skip_b ;  out' = res_W@z + res_b + out
// Block: 256 threads, 64 time cols. Thread tile 8 rows x 4 cols.
// ---------------------------------------------------------------------------
__global__ __launch_bounds__(256, 2)
void k_layer(const float* __restrict__ outPrev, float* __restrict__ outNext,
             float* __restrict__ skip, const float* __restrict__ f,
             const float* __restrict__ AT,   // (272,128) this layer
             const float* __restrict__ SRT,  // (64,128)
             const float* __restrict__ convB, const float* __restrict__ skipB,
             const float* __restrict__ resB, int d)
{
    __shared__ __align__(16) float s_X[64 * 128];     // residual tile + halo [c][u]
    __shared__ __align__(16) float s_Z[64 * TILE_T];  // z tile [c][tt]
    __shared__ __align__(16) float s_A[16 * 128];     // weight chunk [kk][o]
    __shared__ __align__(16) float s_B[16 * TILE_T];  // cond-feature chunk [kk][tt]

    const int tid = threadIdx.x;
    const int i = tid >> 4;          // 0..15 -> rows 8i
    const int j = tid & 15;          // 0..15 -> cols 4j
    const int b = blockIdx.x >> 8;   // 256 tiles per batch
    const int t0 = (blockIdx.x & 255) * TILE_T;

    const int W = TILE_T + 2 * d;    // staged width (<=128)
    const float* outb = outPrev + b * 64 * T_LEN;
    for (int idx = tid; idx < 64 * W; idx += 256) {
        int c = idx / W, u = idx - c * W;
        int g = t0 - 2 * d + u;
        s_X[c * 128 + u] = (g >= 0) ? outb[c * T_LEN + g] : 0.f;   // causal left zero-pad
    }

    float acc[8][4];
#pragma unroll
    for (int r = 0; r < 8; ++r)
#pragma unroll
        for (int cc = 0; cc < 4; ++cc) acc[r][cc] = 0.f;

    const float* fb = f + b * FCH * T_LEN + t0;

    // ---------------- GEMM1: h = A^T x [X taps ; F] ----------------
    for (int kc = 0; kc < 272; kc += 16) {
        __syncthreads();
        {   // stage 16x128 weight chunk (coalesced float4)
            const float4* src = (const float4*)(AT + kc * 128);
            float4* dst = (float4*)s_A;
            dst[tid] = src[tid];
            dst[tid + 256] = src[tid + 256];
        }
        if (kc >= 192) {   // stage 16 cond-feature rows
            int base = kc - 192;
            for (int idx2 = tid; idx2 < 16 * TILE_T; idx2 += 256) {
                int rr = idx2 >> 6, tt = idx2 & 63;
                s_B[rr * TILE_T + tt] = fb[(base + rr) * T_LEN + tt];
            }
        }
        __syncthreads();

        if (kc < 192) {
            const int tap = kc >> 6;       // constant within chunk (64 | 16)
            const int cbase = kc & 63;
            const float* Bb = s_X + cbase * 128 + tap * d + 4 * j;
#pragma unroll
            for (int kk = 0; kk < 16; ++kk) {
                const float* Br = Bb + kk * 128;
                float b0 = Br[0], b1 = Br[1], b2 = Br[2], b3 = Br[3];
                const float4* Ar = (const float4*)(s_A + kk * 128 + 8 * i);
                float4 aL = Ar[0], aH = Ar[1];
                float av[8] = {aL.x, aL.y, aL.z, aL.w, aH.x, aH.y, aH.z, aH.w};
#pragma unroll
                for (int r = 0; r < 8; ++r) {
                    acc[r][0] = fmaf(av[r], b0, acc[r][0]);
                    acc[r][1] = fmaf(av[r], b1, acc[r][1]);
                    acc[r][2] = fmaf(av[r], b2, acc[r][2]);
                    acc[r][3] = fmaf(av[r], b3, acc[r][3]);
                }
            }
        } else {
            const float* Bb = s_B + 4 * j;
#pragma unroll
            for (int kk = 0; kk < 16; ++kk) {
                const float* Br = Bb + kk * TILE_T;
                float b0 = Br[0], b1 = Br[1], b2 = Br[2], b3 = Br[3];
                const float4* Ar = (const float4*)(s_A + kk * 128 + 8 * i);
                float4 aL = Ar[0], aH = Ar[1];
                float av[8] = {aL.x, aL.y, aL.z, aL.w, aH.x, aH.y, aH.z, aH.w};
#pragma unroll
                for (int r = 0; r < 8; ++r) {
                    acc[r][0] = fmaf(av[r], b0, acc[r][0]);
                    acc[r][1] = fmaf(av[r], b1, acc[r][1]);
                    acc[r][2] = fmaf(av[r], b2, acc[r][2]);
                    acc[r][3] = fmaf(av[r], b3, acc[r][3]);
                }
            }
        }
    }

    // bias
#pragma unroll
    for (int r = 0; r < 8; ++r) {
        float bv = convB[8 * i + r];
#pragma unroll
        for (int cc = 0; cc < 4; ++cc) acc[r][cc] += bv;
    }

    // ---------------- gated activation: z = tanh(a)*sigmoid(g) ----------------
    __syncthreads();
    if (i >= 8) {                          // g rows (channels 64..127)
#pragma unroll
        for (int r = 0; r < 8; ++r) {
            int c = 8 * i - 64 + r;
#pragma unroll
            for (int cc = 0; cc < 4; ++cc)
                s_Z[c * TILE_T + 4 * j + cc] = 1.f / (1.f + expf(-acc[r][cc]));
        }
    }
    __syncthreads();
    if (i < 8) {                           // a rows (channels 0..63)
#pragma unroll
        for (int r = 0; r < 8; ++r) {
            int c = 8 * i + r;
#pragma unroll
            for (int cc = 0; cc < 4; ++cc) {
                int zi = c * TILE_T + 4 * j + cc;
                s_Z[zi] = tanhf(acc[r][cc]) * s_Z[zi];
            }
        }
    }

    // ---------------- GEMM2: [skip_d ; res_d] = SRT^T x Z ----------------
    float acc2[8][4];
#pragma unroll
    for (int r = 0; r < 8; ++r)
#pragma unroll
        for (int cc = 0; cc < 4; ++cc) acc2[r][cc] = 0.f;

    for (int kc = 0; kc < 64; kc += 16) {
        __syncthreads();
        const float4* src = (const float4*)(SRT + kc * 128);
        float4* dst = (float4*)s_A;
        dst[tid] = src[tid];
        dst[tid + 256] = src[tid + 256];
        __syncthreads();
#pragma unroll
        for (int kk = 0; kk < 16; ++kk) {
            const float* Br = s_Z + (kc + kk) * TILE_T + 4 * j;
            float b0 = Br[0], b1 = Br[1], b2 = Br[2], b3 = Br[3];
            const float4* Ar = (const float4*)(s_A + kk * 128 + 8 * i);
            float4 aL = Ar[0], aH = Ar[1];
            float av[8] = {aL.x, aL.y, aL.z, aL.w, aH.x, aH.y, aH.z, aH.w};
#pragma unroll
            for (int r = 0; r < 8; ++r) {
                acc2[r][0] = fmaf(av[r], b0, acc2[r][0]);
                acc2[r][1] = fmaf(av[r], b1, acc2[r][1]);
                acc2[r][2] = fmaf(av[r], b2, acc2[r][2]);
                acc2[r][3] = fmaf(av[r], b3, acc2[r][3]);
            }
        }
    }

    // ---------------- epilogue ----------------
    const int colBase = t0 + 4 * j;
    if (i < 8) {            // skip channels 8i..8i+7
#pragma unroll
        for (int r = 0; r < 8; ++r) {
            int c = 8 * i + r;
            float* sp = skip + (b * 64 + c) * T_LEN + colBase;
            float sb = skipB[c];
#pragma unroll
            for (int cc = 0; cc < 4; ++cc) sp[cc] += acc2[r][cc] + sb;
        }
    } else {                // residual channels
#pragma unroll
        for (int r = 0; r < 8; ++r) {
            int c = 8 * i - 64 + r;
            float* op = outNext + (b * 64 + c) * T_LEN + colBase;
            float rb = resB[c];
#pragma unroll
            for (int cc = 0; cc < 4; ++cc)
                op[cc] = acc2[r][cc] + rb + s_X[c * 128 + 2 * d + 4 * j + cc];
        }
    }
}

// ---------------------------------------------------------------------------
// h2 = relu(last1_W @ relu(skip) + last1_b)   (64x64 GEMM)
// ---------------------------------------------------------------------------
__global__ __launch_bounds__(256)
void k_last1(const float* __restrict__ skip, const float* __restrict__ W1,
             const float* __restrict__ b1, float* __restrict__ h2) {
    __shared__ __align__(16) float s_S[64 * 128];
    __shared__ __align__(16) float s_W[64 * 64];
    const int tid = threadIdx.x;
    const int i = tid >> 5;          // 0..7 -> rows 8i
    const int j = tid & 31;          // 0..31 -> cols 4j
    const int b = blockIdx.x >> 7;   // 128 tiles per batch
    const int t0 = (blockIdx.x & 127) * 128;

    const float* sb = skip + b * 64 * T_LEN + t0;
    for (int idx = tid; idx < 64 * 128; idx += 256) {
        int c = idx >> 7, tt = idx & 127;
        float v = sb[c * T_LEN + tt];
        s_S[idx] = v > 0.f ? v : 0.f;
    }
    for (int idx = tid; idx < 64 * 64; idx += 256) {
        int o = idx >> 6, c = idx & 63;
        s_W[c * 64 + o] = W1[idx];
    }
    __syncthreads();

    float acc[8][4];
#pragma unroll
    for (int r = 0; r < 8; ++r)
#pragma unroll
        for (int cc = 0; cc < 4; ++cc) acc[r][cc] = 0.f;

    for (int k = 0; k < 64; ++k) {
        const float* Br = s_S + k * 128 + 4 * j;
        float b0 = Br[0], b1v = Br[1], b2 = Br[2], b3 = Br[3];
        const float4* Ar = (const float4*)(s_W + k * 64 + 8 * i);
        float4 aL = Ar[0], aH = Ar[1];
        float av[8] = {aL.x, aL.y, aL.z, aL.w, aH.x, aH.y, aH.z, aH.w};
#pragma unroll
        for (int r = 0; r < 8; ++r) {
            acc[r][0] = fmaf(av[r], b0, acc[r][0]);
            acc[r][1] = fmaf(av[r], b1v, acc[r][1]);
            acc[r][2] = fmaf(av[r], b2, acc[r][2]);
            acc[r][3] = fmaf(av[r], b3, acc[r][3]);
        }
    }

    float* hb = h2 + b * 64 * T_LEN + t0 + 4 * j;
#pragma unroll
    for (int r = 0; r < 8; ++r) {
        int o = 8 * i + r;
        float bias = b1[o];
#pragma unroll
        for (int cc = 0; cc < 4; ++cc) {
            float v = acc[r][cc] + bias;
            hb[o * T_LEN + cc] = v > 0.f ? v : 0.f;
        }
    }
}

// ---------------------------------------------------------------------------
// out = last2_W @ h2 + last2_b   (256x64 GEMM)
// ---------------------------------------------------------------------------
__global__ __launch_bounds__(256)
void k_last2(const float* __restrict__ h2, const float* __restrict__ W2,
             const float* __restrict__ b2, float* __restrict__ out) {
    __shared__ __align__(16) float s_H[64 * 64];
    __shared__ __align__(16) float s_W[16 * 256];
    const int tid = threadIdx.x;
    const int i = tid >> 3;          // 0..31 -> rows 8i
    const int j = tid & 7;           // 0..7  -> cols 8j
    const int b = blockIdx.x >> 8;   // 256 tiles per batch
    const int t0 = (blockIdx.x & 255) * 64;

    const float* hb = h2 + b * 64 * T_LEN + t0;
    for (int idx = tid; idx < 64 * 64; idx += 256) {
        int c = idx >> 6, tt = idx & 63;
        s_H[idx] = hb[c * T_LEN + tt];
    }

    float acc[8][8];
#pragma unroll
    for (int r = 0; r < 8; ++r)
#pragma unroll
        for (int cc = 0; cc < 8; ++cc) acc[r][cc] = 0.f;

    for (int kc = 0; kc < 64; kc += 16) {
        __syncthreads();
        for (int idx = tid; idx < 16 * 256; idx += 256) {
            int o = idx & 255, kk = idx >> 8;
            s_W[kk * 256 + o] = W2[o * 64 + kc + kk];
        }
        __syncthreads();
#pragma unroll
        for (int kk = 0; kk < 16; ++kk) {
            const float4* Br4 = (const float4*)(s_H + (kc + kk) * 64 + 8 * j);
            float4 bL = Br4[0], bH = Br4[1];
            float bv[8] = {bL.x, bL.y, bL.z, bL.w, bH.x, bH.y, bH.z, bH.w};
            const float4* Ar = (const float4*)(s_W + kk * 256 + 8 * i);
            float4 aL = Ar[0], aH = Ar[1];
            float av[8] = {aL.x, aL.y, aL.z, aL.w, aH.x, aH.y, aH.z, aH.w};
#pragma unroll
            for (int r = 0; r < 8; ++r)
#pragma unroll
                for (int cc = 0; cc < 8; ++cc)
                    acc[r][cc] = fmaf(av[r], bv[cc], acc[r][cc]);
        }
    }

    float* ob = out + b * 256 * T_LEN + t0 + 8 * j;
#pragma unroll
    for (int r = 0; r < 8; ++r) {
        int o = 8 * i + r;
        float bias = b2[o];
#pragma unroll
        for (int cc = 0; cc < 8; ++cc)
            ob[o * T_LEN + cc] = acc[r][cc] + bias;
    }
}

// ---------------------------------------------------------------------------
extern "C" void kernel_launch(void* const* d_in, const int* in_sizes, int n_in,
                              void* d_out, int out_size, void* d_ws, size_t ws_size,
                              hipStream_t stream) {
    const int*   x        = (const int*)  d_in[0];
    const float* feature  = (const float*)d_in[1];
    const float* firstW   = (const float*)d_in[2];
    const float* firstb   = (const float*)d_in[3];
    const float* convW    = (const float*)d_in[4];
    const float* convB    = (const float*)d_in[5];
    const float* condW    = (const float*)d_in[6];
    const float* skipW    = (const float*)d_in[7];
    const float* skipB    = (const float*)d_in[8];
    const float* resW     = (const float*)d_in[9];
    const float* resB     = (const float*)d_in[10];
    const float* last1W   = (const float*)d_in[11];
    const float* last1b   = (const float*)d_in[12];
    const float* last2W   = (const float*)d_in[13];
    const float* last2b   = (const float*)d_in[14];
    const float* convinW  = (const float*)d_in[15];
    const float* upK      = (const float*)d_in[16];

    float* ws   = (float*)d_ws;
    float* f0   = ws;                    // 2*80*64
    float* f1   = f0 + 10240;            // 2*80*256
    float* f2   = f1 + 40960;            // 2*80*1024
    float* f3   = f2 + 163840;           // 2*80*4096
    float* ff   = f3 + 655360;           // 2*80*16384
    float* outA = ff + 2621440;          // 2*64*16384
    float* outB = outA + 2097152;
    float* skip = outB + 2097152;
    float* AT   = skip + 2097152;        // 24*272*128
    float* SRT  = AT + 835584;           // 24*64*128

    int n;
    n = NB * RCH * T_LEN;
    k_embed<<<(n + 255) / 256, 256, 0, stream>>>(x, firstW, firstb, outA, skip);
    n = NB * FCH * 64;
    k_convin<<<(n + 255) / 256, 256, 0, stream>>>(feature, convinW, f0);
    k_up<<<(NB * FCH * 256 + 255) / 256, 256, 0, stream>>>(f0, f1, upK + 0, 64);
    k_up<<<(NB * FCH * 1024 + 255) / 256, 256, 0, stream>>>(f1, f2, upK + 9, 256);
    k_up<<<(NB * FCH * 4096 + 255) / 256, 256, 0, stream>>>(f2, f3, upK + 18, 1024);
    k_up<<<(NB * FCH * 16384 + 255) / 256, 256, 0, stream>>>(f3, ff, upK + 27, 4096);
    n = NLAYERS * 272 * 128 + NLAYERS * 64 * 128;
    k_pack<<<(n + 255) / 256, 256, 0, stream>>>(convW, condW, skipW, resW, AT, SRT);

    float* po = outA;
    float* pn = outB;
    for (int l = 0; l < NLAYERS; ++l) {
        int d = 1 << (l % 6);
        k_layer<<<NB * (T_LEN / TILE_T), 256, 0, stream>>>(
            po, pn, skip, ff, AT + l * 272 * 128, SRT + l * 64 * 128,
            convB + l * 128, skipB + l * 64, resB + l * 64, d);
        float* tmp = po; po = pn; pn = tmp;
    }

    float* h2 = pn;   // outB after 24 layers (residual stream no longer needed)
    k_last1<<<NB * (T_LEN / 128), 256, 0, stream>>>(skip, last1W, last1b, h2);
    k_last2<<<NB * (T_LEN / 64), 256, 0, stream>>>(h2, last2W, last2b, (float*)d_out);
}

// Round 2
// 554.632 us; speedup vs baseline: 3.1904x; 3.1904x over previous
//
#include <hip/hip_runtime.h>
#include <math.h>

#define T_LEN   16384
#define NB      2
#define FCH     80
#define NLAYERS 24
#define TFRAMES 68

typedef __attribute__((ext_vector_type(8))) short bf16x8;
typedef __attribute__((ext_vector_type(4))) float f32x4;

static __device__ inline unsigned short f2bf(float f) {
    unsigned int u = __float_as_uint(f);
    unsigned int r = (u + 0x7FFFu + ((u >> 16) & 1u)) >> 16;
    return (unsigned short)r;
}

// ---------------------------------------------------------------------------
// Embedding gather -> time-major fp32 + bf16 residual, zero skip
// ---------------------------------------------------------------------------
__global__ void k_embed(const int* __restrict__ x, const float* __restrict__ firstW,
                        const float* __restrict__ firstb,
                        float* __restrict__ outF, unsigned short* __restrict__ outH,
                        float* __restrict__ skip) {
    int idx = blockIdx.x * 256 + threadIdx.x;
    if (idx >= NB * T_LEN * 64) return;
    int c = idx & 63;
    int t = (idx >> 6) & (T_LEN - 1);
    int b = idx >> 20;
    int xs = (t == 0) ? 0 : x[b * T_LEN + t - 1];
    float v = firstW[c * 256 + xs] + firstb[c];
    outF[idx] = v;
    outH[idx] = f2bf(v);
    skip[idx] = 0.f;
}

// ---------------------------------------------------------------------------
// ConvIn: valid conv, kernel 5, (B,80,68) -> (B,80,64)   (c-major, fp32)
// ---------------------------------------------------------------------------
__global__ void k_convin(const float* __restrict__ feat, const float* __restrict__ W,
                         float* __restrict__ f0) {
    int idx = blockIdx.x * 256 + threadIdx.x;
    if (idx >= NB * FCH * 64) return;
    int t = idx & 63;
    int o = (idx >> 6) % FCH;
    int b = idx / (64 * FCH);
    const float* fb = feat + b * FCH * TFRAMES;
    const float* wo = W + o * FCH * 5;
    float acc = 0.f;
    for (int i = 0; i < FCH; ++i) {
        const float* fi = fb + i * TFRAMES + t;
        const float* wi = wo + i * 5;
#pragma unroll
        for (int k = 0; k < 5; ++k) acc += fi[k] * wi[k];
    }
    f0[idx] = acc;
}

// ---------------------------------------------------------------------------
// Upsample stage (x4 repeat + 9-tap smooth), fp32 c-major
// ---------------------------------------------------------------------------
__global__ void k_up(const float* __restrict__ in, float* __restrict__ out,
                     const float* __restrict__ kern, int Tin) {
    int Tout = Tin * 4;
    int idx = blockIdx.x * 256 + threadIdx.x;
    if (idx >= NB * FCH * Tout) return;
    int t = idx % Tout;
    int bc = idx / Tout;
    const float* ib = in + bc * Tin;
    float acc = 0.f;
#pragma unroll
    for (int k = 0; k < 9; ++k) {
        int u = t + k - 4;
        if (u >= 0 && u < Tout) acc += kern[k] * ib[u >> 2];
    }
    out[idx] = acc;
}

// ---------------------------------------------------------------------------
// Last upsample stage -> bf16, TIME-MAJOR [b][t][96] (c>=80 zero-padded)
// ---------------------------------------------------------------------------
__global__ void k_up_last(const float* __restrict__ in, unsigned short* __restrict__ outH,
                          const float* __restrict__ kern) {
    int idx = blockIdx.x * 256 + threadIdx.x;
    if (idx >= NB * T_LEN * 96) return;
    int c = idx % 96;
    int g = idx / 96;
    int t = g & (T_LEN - 1);
    int b = g >> 14;
    float acc = 0.f;
    if (c < 80) {
        const float* ib = in + ((size_t)b * 80 + c) * 4096;
#pragma unroll
        for (int k = 0; k < 9; ++k) {
            int u = t + k - 4;
            if (u >= 0 && u < T_LEN) acc += kern[k] * ib[u >> 2];
        }
    }
    outH[idx] = f2bf(acc);
}

// ---------------------------------------------------------------------------
// Pack weights to bf16 GEMM layouts:
// ATb[l][o][k], k in [0,288): k<192 -> convW[l][o][k&63][k>>6];
//                             k-192<80 -> condW ; else 0
// SRTb[l][o2][k], o2<64 skipW else resW ; W1b/W2b straight bf16 copies
// ---------------------------------------------------------------------------
__global__ void k_pack(const float* __restrict__ convW, const float* __restrict__ condW,
                       const float* __restrict__ skipW, const float* __restrict__ resW,
                       const float* __restrict__ last1W, const float* __restrict__ last2W,
                       unsigned short* __restrict__ ATb, unsigned short* __restrict__ SRTb,
                       unsigned short* __restrict__ W1b, unsigned short* __restrict__ W2b) {
    int idx = blockIdx.x * 256 + threadIdx.x;
    const int nAT = NLAYERS * 128 * 288;
    const int nSR = NLAYERS * 128 * 64;
    if (idx < nAT) {
        int k = idx % 288;
        int o = (idx / 288) & 127;
        int l = idx / (288 * 128);
        float v = 0.f;
        if (k < 192) v = convW[(((l * 128 + o) * 64) + (k & 63)) * 3 + (k >> 6)];
        else if (k - 192 < 80) v = condW[(l * 128 + o) * 80 + (k - 192)];
        ATb[idx] = f2bf(v);
    } else if (idx < nAT + nSR) {
        int j = idx - nAT;
        int k = j & 63;
        int o2 = (j >> 6) & 127;
        int l = j / (64 * 128);
        float v = (o2 < 64) ? skipW[(l * 64 + o2) * 64 + k]
                            : resW[(l * 64 + (o2 - 64)) * 64 + k];
        SRTb[j] = f2bf(v);
    } else if (idx < nAT + nSR + 4096) {
        int j = idx - nAT - nSR;
        W1b[j] = f2bf(last1W[j]);
    } else if (idx < nAT + nSR + 4096 + 16384) {
        int j = idx - nAT - nSR - 4096;
        W2b[j] = f2bf(last2W[j]);
    }
}

// ---------------------------------------------------------------------------
// Fused WaveNet layer, MFMA bf16. Time-major activations.
// Block = 4 waves, 64 time cols. Wave w owns gate-channel tiles {16w, 16w+64}
// so tanh/sigmoid pair up in-lane. 2 barriers total.
// ---------------------------------------------------------------------------
__global__ __launch_bounds__(256, 2)
void k_layer(const float* __restrict__ prevF, const unsigned short* __restrict__ prevH,
             float* __restrict__ nextF, unsigned short* __restrict__ nextH,
             float* __restrict__ skip, const unsigned short* __restrict__ ffb,
             const unsigned short* __restrict__ ATb, const unsigned short* __restrict__ SRTb,
             const float* __restrict__ convB, const float* __restrict__ skipB,
             const float* __restrict__ resB, int d)
{
    __shared__ __align__(16) unsigned short s_X[128 * 72];  // [u][c] bf16, pad 72
    __shared__ __align__(16) unsigned short s_F[64 * 104];  // [t][kf] bf16, pad 104
    __shared__ __align__(16) unsigned short s_Z[64 * 72];   // [t][c] bf16, pad 72

    const int tid = threadIdx.x;
    const int b   = blockIdx.x >> 8;
    const int t0  = (blockIdx.x & 255) * 64;
    const int W   = 64 + 2 * d;

    // stage residual (bf16, time-major) with causal zero halo
    {
        const unsigned short* xb = prevH + ((size_t)b * T_LEN) * 64;
        for (int idx = tid; idx < W * 8; idx += 256) {
            int u = idx >> 3, seg = idx & 7;
            int g = t0 - 2 * d + u;
            bf16x8 v = {0, 0, 0, 0, 0, 0, 0, 0};
            if (g >= 0) v = *(const bf16x8*)(xb + (size_t)g * 64 + seg * 8);
            *(bf16x8*)(&s_X[u * 72 + seg * 8]) = v;
        }
    }
    // stage cond features (already bf16 time-major, zero-padded to 96)
    {
        const unsigned short* fp = ffb + ((size_t)b * T_LEN + t0) * 96;
        for (int idx = tid; idx < 64 * 12; idx += 256) {
            int t = idx / 12, seg = idx - t * 12;
            *(bf16x8*)(&s_F[t * 104 + seg * 8]) = *(const bf16x8*)(fp + t * 96 + seg * 8);
        }
    }

    const int lane = tid & 63;
    const int wv   = tid >> 6;
    const int col  = lane & 15;   // A-row / B-col / C-col
    const int quad = lane >> 4;

    // preload GEMM1 A-fragments (weights, L2-resident)
    bf16x8 frA[2][9];
#pragma unroll
    for (int p = 0; p < 2; ++p)
#pragma unroll
        for (int ks = 0; ks < 9; ++ks)
            frA[p][ks] = *(const bf16x8*)(ATb + (size_t)(16 * wv + 64 * p + col) * 288
                                          + ks * 32 + quad * 8);

    f32x4 acc[2][4];
#pragma unroll
    for (int p = 0; p < 2; ++p)
#pragma unroll
        for (int nt = 0; nt < 4; ++nt) acc[p][nt] = (f32x4){0.f, 0.f, 0.f, 0.f};

    __syncthreads();

    // GEMM1: h(128 x 64t) = AT^T * [X-taps ; F], K = 288
#pragma unroll
    for (int ks = 0; ks < 9; ++ks) {
#pragma unroll
        for (int nt = 0; nt < 4; ++nt) {
            bf16x8 fB;
            if (ks < 6) {
                int k = ks * 32 + quad * 8;
                int tap = k >> 6, cb = k & 63;
                int u = nt * 16 + col + tap * d;
                fB = *(const bf16x8*)(&s_X[u * 72 + cb]);
            } else {
                int cf = ks * 32 - 192 + quad * 8;
                fB = *(const bf16x8*)(&s_F[(nt * 16 + col) * 104 + cf]);
            }
            acc[0][nt] = __builtin_amdgcn_mfma_f32_16x16x32_bf16(frA[0][ks], fB, acc[0][nt], 0, 0, 0);
            acc[1][nt] = __builtin_amdgcn_mfma_f32_16x16x32_bf16(frA[1][ks], fB, acc[1][nt], 0, 0, 0);
        }
    }

    // bias + gated activation (in-lane: acc[0]=a-channels c, acc[1]=g-channels c+64)
    f32x4 cbA = *(const f32x4*)(convB + 16 * wv + quad * 4);
    f32x4 cbG = *(const f32x4*)(convB + 64 + 16 * wv + quad * 4);
#pragma unroll
    for (int nt = 0; nt < 4; ++nt) {
        unsigned int pk[2];
#pragma unroll
        for (int r2 = 0; r2 < 2; ++r2) {
            float a0 = acc[0][nt][2 * r2] + cbA[2 * r2];
            float a1 = acc[0][nt][2 * r2 + 1] + cbA[2 * r2 + 1];
            float g0 = acc[1][nt][2 * r2] + cbG[2 * r2];
            float g1 = acc[1][nt][2 * r2 + 1] + cbG[2 * r2 + 1];
            float z0 = tanhf(a0) / (1.f + expf(-g0));
            float z1 = tanhf(a1) / (1.f + expf(-g1));
            pk[r2] = (unsigned int)f2bf(z0) | ((unsigned int)f2bf(z1) << 16);
        }
        unsigned int* zp = (unsigned int*)(&s_Z[(nt * 16 + col) * 72 + 16 * wv + quad * 4]);
        zp[0] = pk[0];
        zp[1] = pk[1];
    }

    // preload GEMM2 A-fragments
    bf16x8 frA2[2][2];
#pragma unroll
    for (int p = 0; p < 2; ++p)
#pragma unroll
        for (int ks = 0; ks < 2; ++ks)
            frA2[p][ks] = *(const bf16x8*)(SRTb + (size_t)(16 * wv + 64 * p + col) * 64
                                           + ks * 32 + quad * 8);

    __syncthreads();

    // GEMM2: [skip;res](128 x 64t) = SRT^T * Z, K = 64
    f32x4 acc2[2][4];
#pragma unroll
    for (int p = 0; p < 2; ++p)
#pragma unroll
        for (int nt = 0; nt < 4; ++nt) acc2[p][nt] = (f32x4){0.f, 0.f, 0.f, 0.f};
#pragma unroll
    for (int ks = 0; ks < 2; ++ks) {
#pragma unroll
        for (int nt = 0; nt < 4; ++nt) {
            bf16x8 fz = *(const bf16x8*)(&s_Z[(nt * 16 + col) * 72 + ks * 32 + quad * 8]);
            acc2[0][nt] = __builtin_amdgcn_mfma_f32_16x16x32_bf16(frA2[0][ks], fz, acc2[0][nt], 0, 0, 0);
            acc2[1][nt] = __builtin_amdgcn_mfma_f32_16x16x32_bf16(frA2[1][ks], fz, acc2[1][nt], 0, 0, 0);
        }
    }

    // epilogue: skip RMW (fp32) + residual add (fp32 master) + bf16 mirror
    f32x4 sb4 = *(const f32x4*)(skipB + 16 * wv + quad * 4);
    f32x4 rb4 = *(const f32x4*)(resB + 16 * wv + quad * 4);
#pragma unroll
    for (int nt = 0; nt < 4; ++nt) {
        size_t base = (((size_t)b * T_LEN) + t0 + nt * 16 + col) * 64 + 16 * wv + quad * 4;
        f32x4 s = *(f32x4*)(skip + base);
        f32x4 r = *(const f32x4*)(prevF + base);
#pragma unroll
        for (int e = 0; e < 4; ++e) {
            s[e] += acc2[0][nt][e] + sb4[e];
            r[e] += acc2[1][nt][e] + rb4[e];
        }
        *(f32x4*)(skip + base) = s;
        *(f32x4*)(nextF + base) = r;
        unsigned int p01 = (unsigned int)f2bf(r[0]) | ((unsigned int)f2bf(r[1]) << 16);
        unsigned int p23 = (unsigned int)f2bf(r[2]) | ((unsigned int)f2bf(r[3]) << 16);
        unsigned int* hp = (unsigned int*)(nextH + base);
        hp[0] = p01;
        hp[1] = p23;
    }
}

// ---------------------------------------------------------------------------
// h2 = relu(last1_W @ relu(skip) + b1), MFMA, K=64, out bf16 time-major
// ---------------------------------------------------------------------------
__global__ __launch_bounds__(256)
void k_last1(const float* __restrict__ skip, const unsigned short* __restrict__ W1b,
             const float* __restrict__ b1, unsigned short* __restrict__ h2b) {
    __shared__ __align__(16) unsigned short s_S[64 * 72];
    const int tid = threadIdx.x;
    const int b = blockIdx.x >> 8;
    const int t0 = (blockIdx.x & 255) * 64;
    const float* sp = skip + (((size_t)b * T_LEN) + t0) * 64;
    for (int idx = tid; idx < 64 * 32; idx += 256) {
        int t = idx >> 5, c2 = idx & 31;
        float v0 = sp[t * 64 + 2 * c2];
        float v1 = sp[t * 64 + 2 * c2 + 1];
        v0 = v0 > 0.f ? v0 : 0.f;
        v1 = v1 > 0.f ? v1 : 0.f;
        *(unsigned int*)(&s_S[t * 72 + 2 * c2]) =
            (unsigned int)f2bf(v0) | ((unsigned int)f2bf(v1) << 16);
    }
    const int lane = tid & 63, wv = tid >> 6, col = lane & 15, quad = lane >> 4;
    bf16x8 fa[2];
#pragma unroll
    for (int ks = 0; ks < 2; ++ks)
        fa[ks] = *(const bf16x8*)(W1b + (16 * wv + col) * 64 + ks * 32 + quad * 8);
    f32x4 acc[4];
#pragma unroll
    for (int nt = 0; nt < 4; ++nt) acc[nt] = (f32x4){0.f, 0.f, 0.f, 0.f};
    __syncthreads();
#pragma unroll
    for (int ks = 0; ks < 2; ++ks)
#pragma unroll
        for (int nt = 0; nt < 4; ++nt) {
            bf16x8 fz = *(const bf16x8*)(&s_S[(nt * 16 + col) * 72 + ks * 32 + quad * 8]);
            acc[nt] = __builtin_amdgcn_mfma_f32_16x16x32_bf16(fa[ks], fz, acc[nt], 0, 0, 0);
        }
    f32x4 bb = *(const f32x4*)(b1 + 16 * wv + quad * 4);
#pragma unroll
    for (int nt = 0; nt < 4; ++nt) {
        float h0 = acc[nt][0] + bb[0]; h0 = h0 > 0.f ? h0 : 0.f;
        float h1 = acc[nt][1] + bb[1]; h1 = h1 > 0.f ? h1 : 0.f;
        float h2 = acc[nt][2] + bb[2]; h2 = h2 > 0.f ? h2 : 0.f;
        float h3 = acc[nt][3] + bb[3]; h3 = h3 > 0.f ? h3 : 0.f;
        unsigned short* hp = h2b + (((size_t)b * T_LEN) + t0 + nt * 16 + col) * 64
                             + 16 * wv + quad * 4;
        ((unsigned int*)hp)[0] = (unsigned int)f2bf(h0) | ((unsigned int)f2bf(h1) << 16);
        ((unsigned int*)hp)[1] = (unsigned int)f2bf(h2) | ((unsigned int)f2bf(h3) << 16);
    }
}

// ---------------------------------------------------------------------------
// out(B,256,T) = last2_W @ h2 + b2, MFMA, K=64, output c-major fp32
// ---------------------------------------------------------------------------
__global__ __launch_bounds__(256)
void k_last2(const unsigned short* __restrict__ h2b, const unsigned short* __restrict__ W2b,
             const float* __restrict__ b2, float* __restrict__ out) {
    __shared__ __align__(16) unsigned short s_H[64 * 72];
    const int tid = threadIdx.x;
    const int b = blockIdx.x >> 8;
    const int t0 = (blockIdx.x & 255) * 64;
    const unsigned short* hp = h2b + (((size_t)b * T_LEN) + t0) * 64;
    for (int idx = tid; idx < 64 * 8; idx += 256) {
        int t = idx >> 3, seg = idx & 7;
        *(bf16x8*)(&s_H[t * 72 + seg * 8]) = *(const bf16x8*)(hp + t * 64 + seg * 8);
    }
    const int lane = tid & 63, wv = tid >> 6, col = lane & 15, quad = lane >> 4;
    bf16x8 fa[4][2];
#pragma unroll
    for (int p = 0; p < 4; ++p)
#pragma unroll
        for (int ks = 0; ks < 2; ++ks)
            fa[p][ks] = *(const bf16x8*)(W2b + (size_t)(16 * (wv + 4 * p) + col) * 64
                                         + ks * 32 + quad * 8);
    f32x4 acc[4][4];
#pragma unroll
    for (int p = 0; p < 4; ++p)
#pragma unroll
        for (int nt = 0; nt < 4; ++nt) acc[p][nt] = (f32x4){0.f, 0.f, 0.f, 0.f};
    __syncthreads();
#pragma unroll
    for (int ks = 0; ks < 2; ++ks)
#pragma unroll
        for (int nt = 0; nt < 4; ++nt) {
            bf16x8 fz = *(const bf16x8*)(&s_H[(nt * 16 + col) * 72 + ks * 32 + quad * 8]);
#pragma unroll
            for (int p = 0; p < 4; ++p)
                acc[p][nt] = __builtin_amdgcn_mfma_f32_16x16x32_bf16(fa[p][ks], fz, acc[p][nt], 0, 0, 0);
        }
#pragma unroll
    for (int p = 0; p < 4; ++p) {
        f32x4 bb = *(const f32x4*)(b2 + 16 * (wv + 4 * p) + quad * 4);
#pragma unroll
        for (int nt = 0; nt < 4; ++nt) {
            int t = t0 + nt * 16 + col;
#pragma unroll
            for (int e = 0; e < 4; ++e) {
                int o = 16 * (wv + 4 * p) + quad * 4 + e;
                out[((size_t)b * 256 + o) * T_LEN + t] = acc[p][nt][e] + bb[e];
            }
        }
    }
}

// ---------------------------------------------------------------------------
extern "C" void kernel_launch(void* const* d_in, const int* in_sizes, int n_in,
                              void* d_out, int out_size, void* d_ws, size_t ws_size,
                              hipStream_t stream) {
    const int*   x       = (const int*)  d_in[0];
    const float* feature = (const float*)d_in[1];
    const float* firstW  = (const float*)d_in[2];
    const float* firstb  = (const float*)d_in[3];
    const float* convW   = (const float*)d_in[4];
    const float* convB   = (const float*)d_in[5];
    const float* condW   = (const float*)d_in[6];
    const float* skipW   = (const float*)d_in[7];
    const float* skipB   = (const float*)d_in[8];
    const float* resW    = (const float*)d_in[9];
    const float* resB    = (const float*)d_in[10];
    const float* last1W  = (const float*)d_in[11];
    const float* last1b  = (const float*)d_in[12];
    const float* last2W  = (const float*)d_in[13];
    const float* last2b  = (const float*)d_in[14];
    const float* convinW = (const float*)d_in[15];
    const float* upK     = (const float*)d_in[16];

    float* ws = (float*)d_ws;
    float* f0   = ws;                              // 10240
    float* f1   = f0 + 10240;                      // 40960
    float* f2   = f1 + 40960;                      // 163840
    float* f3   = f2 + 163840;                     // 655360
    unsigned short* ffb = (unsigned short*)(f3 + 655360);      // 3145728 ush
    float* outAF = (float*)d_ws + 2443264;         // 2097152
    float* outBF = outAF + 2097152;
    float* skip  = outBF + 2097152;
    unsigned short* outAH = (unsigned short*)(skip + 2097152); // 2097152 ush
    unsigned short* outBH = outAH + 2097152;
    unsigned short* h2b   = outBH + 2097152;                   // 2097152 ush
    unsigned short* ATb   = h2b + 2097152;                     // 884736 ush
    unsigned short* SRTb  = ATb + 884736;                      // 196608 ush
    unsigned short* W1b   = SRTb + 196608;                     // 4096 ush
    unsigned short* W2b   = W1b + 4096;                        // 16384 ush

    int n;
    n = NB * T_LEN * 64;
    k_embed<<<(n + 255) / 256, 256, 0, stream>>>(x, firstW, firstb, outAF, outAH, skip);
    n = NB * FCH * 64;
    k_convin<<<(n + 255) / 256, 256, 0, stream>>>(feature, convinW, f0);
    k_up<<<(NB * FCH * 256 + 255) / 256, 256, 0, stream>>>(f0, f1, upK + 0, 64);
    k_up<<<(NB * FCH * 1024 + 255) / 256, 256, 0, stream>>>(f1, f2, upK + 9, 256);
    k_up<<<(NB * FCH * 4096 + 255) / 256, 256, 0, stream>>>(f2, f3, upK + 18, 1024);
    n = NB * T_LEN * 96;
    k_up_last<<<(n + 255) / 256, 256, 0, stream>>>(f3, ffb, upK + 27);
    n = NLAYERS * 128 * 288 + NLAYERS * 128 * 64 + 4096 + 16384;
    k_pack<<<(n + 255) / 256, 256, 0, stream>>>(convW, condW, skipW, resW, last1W, last2W,
                                                ATb, SRTb, W1b, W2b);

    float* poF = outAF; unsigned short* poH = outAH;
    float* pnF = outBF; unsigned short* pnH = outBH;
    for (int l = 0; l < NLAYERS; ++l) {
        int d = 1 << (l % 6);
        k_layer<<<NB * 256, 256, 0, stream>>>(poF, poH, pnF, pnH, skip, ffb,
                                              ATb + (size_t)l * 128 * 288,
                                              SRTb + (size_t)l * 128 * 64,
                                              convB + l * 128, skipB + l * 64, resB + l * 64, d);
        float* tf = poF; poF = pnF; pnF = tf;
        unsigned short* th = poH; poH = pnH; pnH = th;
    }

    k_last1<<<NB * 256, 256, 0, stream>>>(skip, W1b, last1b, h2b);
    k_last2<<<NB * 256, 256, 0, stream>>>(h2b, W2b, last2b, (float*)d_out);
}

// Round 3
// 509.003 us; speedup vs baseline: 3.4764x; 1.0896x over previous
//
#include <hip/hip_runtime.h>
#include <math.h>

#define T_LEN   16384
#define NB      2
#define FCH     80
#define NLAYERS 24
#define TFRAMES 68
#define TILE    32

typedef __attribute__((ext_vector_type(8))) short bf16x8;
typedef __attribute__((ext_vector_type(4))) float f32x4;

static __device__ inline unsigned short f2bf(float f) {
    unsigned int u = __float_as_uint(f);
    unsigned int r = (u + 0x7FFFu + ((u >> 16) & 1u)) >> 16;
    return (unsigned short)r;
}

// ---------------------------------------------------------------------------
// Pack: bf16 weight layouts + firstWT (transposed embedding table, bias folded)
// ---------------------------------------------------------------------------
__global__ void k_pack(const float* __restrict__ convW, const float* __restrict__ condW,
                       const float* __restrict__ skipW, const float* __restrict__ resW,
                       const float* __restrict__ last1W, const float* __restrict__ last2W,
                       const float* __restrict__ firstW, const float* __restrict__ firstb,
                       unsigned short* __restrict__ ATb, unsigned short* __restrict__ SRTb,
                       unsigned short* __restrict__ W1b, unsigned short* __restrict__ W2b,
                       float* __restrict__ firstWT) {
    int idx = blockIdx.x * 256 + threadIdx.x;
    const int nAT = NLAYERS * 128 * 288;
    const int nSR = NLAYERS * 128 * 64;
    if (idx < nAT) {
        int k = idx % 288;
        int o = (idx / 288) & 127;
        int l = idx / (288 * 128);
        float v = 0.f;
        if (k < 192) v = convW[(((l * 128 + o) * 64) + (k & 63)) * 3 + (k >> 6)];
        else if (k - 192 < 80) v = condW[(l * 128 + o) * 80 + (k - 192)];
        ATb[idx] = f2bf(v);
    } else if (idx < nAT + nSR) {
        int j = idx - nAT;
        int k = j & 63;
        int o2 = (j >> 6) & 127;
        int l = j / (64 * 128);
        float v = (o2 < 64) ? skipW[(l * 64 + o2) * 64 + k]
                            : resW[(l * 64 + (o2 - 64)) * 64 + k];
        SRTb[j] = f2bf(v);
    } else if (idx < nAT + nSR + 4096) {
        W1b[idx - nAT - nSR] = f2bf(last1W[idx - nAT - nSR]);
    } else if (idx < nAT + nSR + 4096 + 16384) {
        int j = idx - nAT - nSR - 4096;
        W2b[j] = f2bf(last2W[j]);
    } else if (idx < nAT + nSR + 4096 + 16384 + 16384) {
        int j = idx - nAT - nSR - 4096 - 16384;
        int xs = j >> 6, c = j & 63;
        firstWT[j] = firstW[c * 256 + xs] + firstb[c];
    }
}

// ---------------------------------------------------------------------------
// Embedding gather (coalesced via firstWT) + zero skip
// ---------------------------------------------------------------------------
__global__ void k_embed(const int* __restrict__ x, const float* __restrict__ firstWT,
                        float* __restrict__ outF, float* __restrict__ skip) {
    int idx = blockIdx.x * 256 + threadIdx.x;
    if (idx >= NB * T_LEN * 64) return;
    int c = idx & 63;
    int t = (idx >> 6) & (T_LEN - 1);
    int b = idx >> 20;
    int xs = (t == 0) ? 0 : x[b * T_LEN + t - 1];
    outF[idx] = firstWT[xs * 64 + c];
    skip[idx] = 0.f;
}

// ---------------------------------------------------------------------------
// ConvIn: valid conv, kernel 5, (B,80,68) -> (B,80,64)   (c-major, fp32)
// ---------------------------------------------------------------------------
__global__ void k_convin(const float* __restrict__ feat, const float* __restrict__ W,
                         float* __restrict__ f0) {
    int idx = blockIdx.x * 256 + threadIdx.x;
    if (idx >= NB * FCH * 64) return;
    int t = idx & 63;
    int o = (idx >> 6) % FCH;
    int b = idx / (64 * FCH);
    const float* fb = feat + b * FCH * TFRAMES;
    const float* wo = W + o * FCH * 5;
    float acc = 0.f;
    for (int i = 0; i < FCH; ++i) {
        const float* fi = fb + i * TFRAMES + t;
        const float* wi = wo + i * 5;
#pragma unroll
        for (int k = 0; k < 5; ++k) acc += fi[k] * wi[k];
    }
    f0[idx] = acc;
}

// ---------------------------------------------------------------------------
// Upsample stage (x4 repeat + 9-tap smooth), fp32 c-major (t-fastest: coalesced)
// ---------------------------------------------------------------------------
__global__ void k_up(const float* __restrict__ in, float* __restrict__ out,
                     const float* __restrict__ kern, int Tin) {
    int Tout = Tin * 4;
    int idx = blockIdx.x * 256 + threadIdx.x;
    if (idx >= NB * FCH * Tout) return;
    int t = idx % Tout;
    int bc = idx / Tout;
    const float* ib = in + bc * Tin;
    float acc = 0.f;
#pragma unroll
    for (int k = 0; k < 9; ++k) {
        int u = t + k - 4;
        if (u >= 0 && u < Tout) acc += kern[k] * ib[u >> 2];
    }
    out[idx] = acc;
}

// ---------------------------------------------------------------------------
// Last upsample -> bf16 TIME-MAJOR [b][t][96], LDS-staged source frames
// ---------------------------------------------------------------------------
__global__ __launch_bounds__(256)
void k_up_last(const float* __restrict__ in, unsigned short* __restrict__ outH,
               const float* __restrict__ kern) {
    __shared__ float sF[18 * 80];   // [fr][c]
    const int tid = threadIdx.x;
    const int b  = blockIdx.x >> 8;
    const int t0 = (blockIdx.x & 255) * 64;
    const int fr0 = (t0 >> 2) - 1;

    for (int idx = tid; idx < 18 * 80; idx += 256) {
        int c = idx / 18, fr = idx - c * 18;       // fr fastest -> 18-float runs
        int gfr = fr0 + fr;
        float v = 0.f;
        if (gfr >= 0 && gfr < 4096) v = in[((size_t)b * 80 + c) * 4096 + gfr];
        sF[fr * 80 + c] = v;
    }
    float kr[9];
#pragma unroll
    for (int k = 0; k < 9; ++k) kr[k] = kern[k];
    __syncthreads();

    for (int idx = tid; idx < 64 * 96; idx += 256) {
        int c = idx % 96;
        int t = idx / 96;
        float acc = 0.f;
        if (c < 80) {
            int ubase = t0 + t - 4;
#pragma unroll
            for (int k = 0; k < 9; ++k) {
                int fr = ((ubase + k) >> 2) - fr0;
                acc += kr[k] * sF[fr * 80 + c];
            }
        }
        outH[((size_t)b * T_LEN + t0 + t) * 96 + c] = f2bf(acc);
    }
}

// ---------------------------------------------------------------------------
// Fused WaveNet layer, MFMA bf16, 32-col tiles, 4 blocks/CU.
// Stages residual straight from fp32 master (no bf16 mirror buffer).
// ---------------------------------------------------------------------------
__global__ __launch_bounds__(256, 4)
void k_layer(const float* __restrict__ prevF, float* __restrict__ nextF,
             float* __restrict__ skip, const unsigned short* __restrict__ ffb,
             const unsigned short* __restrict__ ATb, const unsigned short* __restrict__ SRTb,
             const float* __restrict__ convB, const float* __restrict__ skipB,
             const float* __restrict__ resB, int d)
{
    __shared__ __align__(16) unsigned short s_X[96 * 72];   // [u][c] bf16
    __shared__ __align__(16) unsigned short s_Z[32 * 72];   // [t][c] bf16

    const int tid = threadIdx.x;
    const int b   = blockIdx.x >> 9;
    const int t0  = (blockIdx.x & 511) * TILE;
    const int W   = TILE + 2 * d;

    // stage residual tile+halo: fp32 -> bf16, causal zero pad
    {
        const float* xb = prevF + ((size_t)b * T_LEN) * 64;
        for (int idx = tid; idx < W * 8; idx += 256) {
            int u = idx >> 3, seg = idx & 7;
            int g = t0 - 2 * d + u;
            bf16x8 v = {0, 0, 0, 0, 0, 0, 0, 0};
            if (g >= 0) {
                const float* p = xb + (size_t)g * 64 + seg * 8;
                f32x4 a0 = *(const f32x4*)p;
                f32x4 a1 = *(const f32x4*)(p + 4);
                v[0] = (short)f2bf(a0[0]); v[1] = (short)f2bf(a0[1]);
                v[2] = (short)f2bf(a0[2]); v[3] = (short)f2bf(a0[3]);
                v[4] = (short)f2bf(a1[0]); v[5] = (short)f2bf(a1[1]);
                v[6] = (short)f2bf(a1[2]); v[7] = (short)f2bf(a1[3]);
            }
            *(bf16x8*)(&s_X[u * 72 + seg * 8]) = v;
        }
    }

    const int lane = tid & 63;
    const int wv   = tid >> 6;
    const int col  = lane & 15;
    const int quad = lane >> 4;

    // preload GEMM1 A-fragments (weights, L2-resident)
    bf16x8 frA[2][9];
#pragma unroll
    for (int p = 0; p < 2; ++p)
#pragma unroll
        for (int ks = 0; ks < 9; ++ks)
            frA[p][ks] = *(const bf16x8*)(ATb + (size_t)(16 * wv + 64 * p + col) * 288
                                          + ks * 32 + quad * 8);

    f32x4 acc[2][2];
#pragma unroll
    for (int p = 0; p < 2; ++p)
#pragma unroll
        for (int nt = 0; nt < 2; ++nt) acc[p][nt] = (f32x4){0.f, 0.f, 0.f, 0.f};

    const unsigned short* fp = ffb + ((size_t)b * T_LEN + t0) * 96;

    __syncthreads();

    // GEMM1: h(128 x 32t) = AT^T * [X-taps ; F], K = 288
#pragma unroll
    for (int ks = 0; ks < 9; ++ks) {
#pragma unroll
        for (int nt = 0; nt < 2; ++nt) {
            bf16x8 fB;
            if (ks < 6) {
                int k = ks * 32 + quad * 8;
                int tap = k >> 6, cb = k & 63;
                int u = nt * 16 + col + tap * d;
                fB = *(const bf16x8*)(&s_X[u * 72 + cb]);
            } else {
                fB = *(const bf16x8*)(fp + (nt * 16 + col) * 96 + (ks - 6) * 32 + quad * 8);
            }
            acc[0][nt] = __builtin_amdgcn_mfma_f32_16x16x32_bf16(frA[0][ks], fB, acc[0][nt], 0, 0, 0);
            acc[1][nt] = __builtin_amdgcn_mfma_f32_16x16x32_bf16(frA[1][ks], fB, acc[1][nt], 0, 0, 0);
        }
    }

    // bias + gated activation (in-lane), z -> s_Z bf16
    f32x4 cbA = *(const f32x4*)(convB + 16 * wv + quad * 4);
    f32x4 cbG = *(const f32x4*)(convB + 64 + 16 * wv + quad * 4);
#pragma unroll
    for (int nt = 0; nt < 2; ++nt) {
        unsigned int pk[2];
#pragma unroll
        for (int r2 = 0; r2 < 2; ++r2) {
            float z01[2];
#pragma unroll
            for (int e = 0; e < 2; ++e) {
                float a = acc[0][nt][2 * r2 + e] + cbA[2 * r2 + e];
                float g = acc[1][nt][2 * r2 + e] + cbG[2 * r2 + e];
                float th = 1.f - 2.f * __builtin_amdgcn_rcpf(__expf(2.f * a) + 1.f);
                float sg = __builtin_amdgcn_rcpf(1.f + __expf(-g));
                z01[e] = th * sg;
            }
            pk[r2] = (unsigned int)f2bf(z01[0]) | ((unsigned int)f2bf(z01[1]) << 16);
        }
        unsigned int* zp = (unsigned int*)(&s_Z[(nt * 16 + col) * 72 + 16 * wv + quad * 4]);
        zp[0] = pk[0];
        zp[1] = pk[1];
    }

    // preload GEMM2 A-fragments
    bf16x8 frA2[2][2];
#pragma unroll
    for (int p = 0; p < 2; ++p)
#pragma unroll
        for (int ks = 0; ks < 2; ++ks)
            frA2[p][ks] = *(const bf16x8*)(SRTb + (size_t)(16 * wv + 64 * p + col) * 64
                                           + ks * 32 + quad * 8);

    __syncthreads();

    // GEMM2: [skip;res](128 x 32t) = SRT^T * Z, K = 64
    f32x4 acc2[2][2];
#pragma unroll
    for (int p = 0; p < 2; ++p)
#pragma unroll
        for (int nt = 0; nt < 2; ++nt) acc2[p][nt] = (f32x4){0.f, 0.f, 0.f, 0.f};
#pragma unroll
    for (int ks = 0; ks < 2; ++ks) {
#pragma unroll
        for (int nt = 0; nt < 2; ++nt) {
            bf16x8 fz = *(const bf16x8*)(&s_Z[(nt * 16 + col) * 72 + ks * 32 + quad * 8]);
            acc2[0][nt] = __builtin_amdgcn_mfma_f32_16x16x32_bf16(frA2[0][ks], fz, acc2[0][nt], 0, 0, 0);
            acc2[1][nt] = __builtin_amdgcn_mfma_f32_16x16x32_bf16(frA2[1][ks], fz, acc2[1][nt], 0, 0, 0);
        }
    }

    // epilogue: skip fp32 RMW + residual fp32 add
    f32x4 sb4 = *(const f32x4*)(skipB + 16 * wv + quad * 4);
    f32x4 rb4 = *(const f32x4*)(resB + 16 * wv + quad * 4);
#pragma unroll
    for (int nt = 0; nt < 2; ++nt) {
        size_t base = (((size_t)b * T_LEN) + t0 + nt * 16 + col) * 64 + 16 * wv + quad * 4;
        f32x4 s = *(f32x4*)(skip + base);
        f32x4 r = *(const f32x4*)(prevF + base);
#pragma unroll
        for (int e = 0; e < 4; ++e) {
            s[e] += acc2[0][nt][e] + sb4[e];
            r[e] += acc2[1][nt][e] + rb4[e];
        }
        *(f32x4*)(skip + base) = s;
        *(f32x4*)(nextF + base) = r;
    }
}

// ---------------------------------------------------------------------------
// h2 = relu(last1_W @ relu(skip) + b1), MFMA, K=64, out bf16 time-major
// ---------------------------------------------------------------------------
__global__ __launch_bounds__(256)
void k_last1(const float* __restrict__ skip, const unsigned short* __restrict__ W1b,
             const float* __restrict__ b1, unsigned short* __restrict__ h2b) {
    __shared__ __align__(16) unsigned short s_S[64 * 72];
    const int tid = threadIdx.x;
    const int b = blockIdx.x >> 8;
    const int t0 = (blockIdx.x & 255) * 64;
    const float* sp = skip + (((size_t)b * T_LEN) + t0) * 64;
    for (int idx = tid; idx < 64 * 32; idx += 256) {
        int t = idx >> 5, c2 = idx & 31;
        float v0 = sp[t * 64 + 2 * c2];
        float v1 = sp[t * 64 + 2 * c2 + 1];
        v0 = v0 > 0.f ? v0 : 0.f;
        v1 = v1 > 0.f ? v1 : 0.f;
        *(unsigned int*)(&s_S[t * 72 + 2 * c2]) =
            (unsigned int)f2bf(v0) | ((unsigned int)f2bf(v1) << 16);
    }
    const int lane = tid & 63, wv = tid >> 6, col = lane & 15, quad = lane >> 4;
    bf16x8 fa[2];
#pragma unroll
    for (int ks = 0; ks < 2; ++ks)
        fa[ks] = *(const bf16x8*)(W1b + (16 * wv + col) * 64 + ks * 32 + quad * 8);
    f32x4 acc[4];
#pragma unroll
    for (int nt = 0; nt < 4; ++nt) acc[nt] = (f32x4){0.f, 0.f, 0.f, 0.f};
    __syncthreads();
#pragma unroll
    for (int ks = 0; ks < 2; ++ks)
#pragma unroll
        for (int nt = 0; nt < 4; ++nt) {
            bf16x8 fz = *(const bf16x8*)(&s_S[(nt * 16 + col) * 72 + ks * 32 + quad * 8]);
            acc[nt] = __builtin_amdgcn_mfma_f32_16x16x32_bf16(fa[ks], fz, acc[nt], 0, 0, 0);
        }
    f32x4 bb = *(const f32x4*)(b1 + 16 * wv + quad * 4);
#pragma unroll
    for (int nt = 0; nt < 4; ++nt) {
        float h0 = acc[nt][0] + bb[0]; h0 = h0 > 0.f ? h0 : 0.f;
        float h1 = acc[nt][1] + bb[1]; h1 = h1 > 0.f ? h1 : 0.f;
        float h2 = acc[nt][2] + bb[2]; h2 = h2 > 0.f ? h2 : 0.f;
        float h3 = acc[nt][3] + bb[3]; h3 = h3 > 0.f ? h3 : 0.f;
        unsigned short* hp = h2b + (((size_t)b * T_LEN) + t0 + nt * 16 + col) * 64
                             + 16 * wv + quad * 4;
        ((unsigned int*)hp)[0] = (unsigned int)f2bf(h0) | ((unsigned int)f2bf(h1) << 16);
        ((unsigned int*)hp)[1] = (unsigned int)f2bf(h2) | ((unsigned int)f2bf(h3) << 16);
    }
}

// ---------------------------------------------------------------------------
// out(B,256,T) = last2_W @ h2 + b2, MFMA, K=64, output c-major fp32
// ---------------------------------------------------------------------------
__global__ __launch_bounds__(256)
void k_last2(const unsigned short* __restrict__ h2b, const unsigned short* __restrict__ W2b,
             const float* __restrict__ b2, float* __restrict__ out) {
    __shared__ __align__(16) unsigned short s_H[64 * 72];
    const int tid = threadIdx.x;
    const int b = blockIdx.x >> 8;
    const int t0 = (blockIdx.x & 255) * 64;
    const unsigned short* hp = h2b + (((size_t)b * T_LEN) + t0) * 64;
    for (int idx = tid; idx < 64 * 8; idx += 256) {
        int t = idx >> 3, seg = idx & 7;
        *(bf16x8*)(&s_H[t * 72 + seg * 8]) = *(const bf16x8*)(hp + t * 64 + seg * 8);
    }
    const int lane = tid & 63, wv = tid >> 6, col = lane & 15, quad = lane >> 4;
    bf16x8 fa[4][2];
#pragma unroll
    for (int p = 0; p < 4; ++p)
#pragma unroll
        for (int ks = 0; ks < 2; ++ks)
            fa[p][ks] = *(const bf16x8*)(W2b + (size_t)(16 * (wv + 4 * p) + col) * 64
                                         + ks * 32 + quad * 8);
    f32x4 acc[4][4];
#pragma unroll
    for (int p = 0; p < 4; ++p)
#pragma unroll
        for (int nt = 0; nt < 4; ++nt) acc[p][nt] = (f32x4){0.f, 0.f, 0.f, 0.f};
    __syncthreads();
#pragma unroll
    for (int ks = 0; ks < 2; ++ks)
#pragma unroll
        for (int nt = 0; nt < 4; ++nt) {
            bf16x8 fz = *(const bf16x8*)(&s_H[(nt * 16 + col) * 72 + ks * 32 + quad * 8]);
#pragma unroll
            for (int p = 0; p < 4; ++p)
                acc[p][nt] = __builtin_amdgcn_mfma_f32_16x16x32_bf16(fa[p][ks], fz, acc[p][nt], 0, 0, 0);
        }
#pragma unroll
    for (int p = 0; p < 4; ++p) {
        f32x4 bb = *(const f32x4*)(b2 + 16 * (wv + 4 * p) + quad * 4);
#pragma unroll
        for (int nt = 0; nt < 4; ++nt) {
            int t = t0 + nt * 16 + col;
#pragma unroll
            for (int e = 0; e < 4; ++e) {
                int o = 16 * (wv + 4 * p) + quad * 4 + e;
                out[((size_t)b * 256 + o) * T_LEN + t] = acc[p][nt][e] + bb[e];
            }
        }
    }
}

// ---------------------------------------------------------------------------
extern "C" void kernel_launch(void* const* d_in, const int* in_sizes, int n_in,
                              void* d_out, int out_size, void* d_ws, size_t ws_size,
                              hipStream_t stream) {
    const int*   x       = (const int*)  d_in[0];
    const float* feature = (const float*)d_in[1];
    const float* firstW  = (const float*)d_in[2];
    const float* firstb  = (const float*)d_in[3];
    const float* convW   = (const float*)d_in[4];
    const float* convB   = (const float*)d_in[5];
    const float* condW   = (const float*)d_in[6];
    const float* skipW   = (const float*)d_in[7];
    const float* skipB   = (const float*)d_in[8];
    const float* resW    = (const float*)d_in[9];
    const float* resB    = (const float*)d_in[10];
    const float* last1W  = (const float*)d_in[11];
    const float* last1b  = (const float*)d_in[12];
    const float* last2W  = (const float*)d_in[13];
    const float* last2b  = (const float*)d_in[14];
    const float* convinW = (const float*)d_in[15];
    const float* upK     = (const float*)d_in[16];

    float* ws = (float*)d_ws;
    float* f0      = ws;                      // 10240
    float* f1      = f0 + 10240;              // 40960
    float* f2      = f1 + 40960;              // 163840
    float* f3      = f2 + 163840;             // 655360
    float* firstWT = f3 + 655360;             // 16384
    float* outAF   = firstWT + 16384;         // 2097152
    float* outBF   = outAF + 2097152;         // 2097152
    float* skip    = outBF + 2097152;         // 2097152
    unsigned short* ffb  = (unsigned short*)(skip + 2097152);  // 3145728
    unsigned short* h2b  = ffb + 3145728;                      // 2097152
    unsigned short* ATb  = h2b + 2097152;                      // 884736
    unsigned short* SRTb = ATb + 884736;                       // 196608
    unsigned short* W1b  = SRTb + 196608;                      // 4096
    unsigned short* W2b  = W1b + 4096;                         // 16384

    int n;
    n = NLAYERS * 128 * 288 + NLAYERS * 128 * 64 + 4096 + 16384 + 16384;
    k_pack<<<(n + 255) / 256, 256, 0, stream>>>(convW, condW, skipW, resW, last1W, last2W,
                                                firstW, firstb, ATb, SRTb, W1b, W2b, firstWT);
    n = NB * T_LEN * 64;
    k_embed<<<(n + 255) / 256, 256, 0, stream>>>(x, firstWT, outAF, skip);
    n = NB * FCH * 64;
    k_convin<<<(n + 255) / 256, 256, 0, stream>>>(feature, convinW, f0);
    k_up<<<(NB * FCH * 256 + 255) / 256, 256, 0, stream>>>(f0, f1, upK + 0, 64);
    k_up<<<(NB * FCH * 1024 + 255) / 256, 256, 0, stream>>>(f1, f2, upK + 9, 256);
    k_up<<<(NB * FCH * 4096 + 255) / 256, 256, 0, stream>>>(f2, f3, upK + 18, 1024);
    k_up_last<<<NB * 256, 256, 0, stream>>>(f3, ffb, upK + 27);

    float* poF = outAF;
    float* pnF = outBF;
    for (int l = 0; l < NLAYERS; ++l) {
        int d = 1 << (l % 6);
        k_layer<<<NB * (T_LEN / TILE), 256, 0, stream>>>(
            poF, pnF, skip, ffb,
            ATb + (size_t)l * 128 * 288, SRTb + (size_t)l * 128 * 64,
            convB + l * 128, skipB + l * 64, resB + l * 64, d);
        float* tf = poF; poF = pnF; pnF = tf;
    }

    k_last1<<<NB * 256, 256, 0, stream>>>(skip, W1b, last1b, h2b);
    k_last2<<<NB * 256, 256, 0, stream>>>(h2b, W2b, last2b, (float*)d_out);
}